// Round 8
// baseline (312.209 us; speedup 1.0000x reference)
//
#include <hip/hip_runtime.h>
#include <hip/hip_fp16.h>

#define NN 100000
#define NE 1000000
#define BSH 7        // bucket shift: 128 cols per bucket
#define BCOLS 128
#define NBUCK 782    // ceil(NN / 128)
#define SBLK 256     // edge-partition blocks for scatter (proven best)
#define SITER 16     // edges per scatter thread
#define CAP 2048     // static per-bucket stride in mid (mean 1279, sd ~36: 21 sigma)
#define OVCAP 16384  // overflow list capacity (statistically never used)

// fp16 helpers -------------------------------------------------------------
__device__ __forceinline__ float2 h2f(unsigned u) {
    union { unsigned u; __half2 h; } c; c.u = u;
    return __half22float2(c.h);
}
__device__ __forceinline__ unsigned f2h2(float a, float b) {
    union { __half2 h; unsigned u; } c; c.h = __floats2half2_rn(a, b);
    return c.u;
}

// fp16 row accumulate: s21 += w * pack16row (3 independent 16B loads) --------
#define ACC_ROW16(base)                                                      \
    {                                                                        \
        const uint4* pr_ = (const uint4*)(base);                             \
        const uint4 A_ = pr_[0];                                             \
        const uint4 B_ = pr_[1];                                             \
        const uint4 C_ = pr_[2];                                             \
        float2 f_;                                                           \
        f_ = h2f(A_.x); s21[0]  = fmaf(w, f_.x, s21[0]);  s21[1]  = fmaf(w, f_.y, s21[1]);  \
        f_ = h2f(A_.y); s21[2]  = fmaf(w, f_.x, s21[2]);  s21[3]  = fmaf(w, f_.y, s21[3]);  \
        f_ = h2f(A_.z); s21[4]  = fmaf(w, f_.x, s21[4]);  s21[5]  = fmaf(w, f_.y, s21[5]);  \
        f_ = h2f(A_.w); s21[6]  = fmaf(w, f_.x, s21[6]);  s21[7]  = fmaf(w, f_.y, s21[7]);  \
        f_ = h2f(B_.x); s21[8]  = fmaf(w, f_.x, s21[8]);  s21[9]  = fmaf(w, f_.y, s21[9]);  \
        f_ = h2f(B_.y); s21[10] = fmaf(w, f_.x, s21[10]); s21[11] = fmaf(w, f_.y, s21[11]); \
        f_ = h2f(B_.z); s21[12] = fmaf(w, f_.x, s21[12]); s21[13] = fmaf(w, f_.y, s21[13]); \
        f_ = h2f(B_.w); s21[14] = fmaf(w, f_.x, s21[14]); s21[15] = fmaf(w, f_.y, s21[15]); \
        f_ = h2f(C_.x); s21[16] = fmaf(w, f_.x, s21[16]); s21[17] = fmaf(w, f_.y, s21[17]); \
        f_ = h2f(C_.y); s21[18] = fmaf(w, f_.x, s21[18]); s21[19] = fmaf(w, f_.y, s21[19]); \
        f_ = h2f(C_.z); s21[20] = fmaf(w, f_.x, s21[20]);                    \
    }

// ---------------------------------------------------------------------------
// K_f: fuse the whole linear chain into Mt[128][24]; zeroes gcur[NBUCK]+ovfn.
// ---------------------------------------------------------------------------
__global__ __launch_bounds__(128) void fuse_kernel(const float* __restrict__ Wu,
                                                   const float* __restrict__ bu,
                                                   const float* __restrict__ Wm,
                                                   const float* __restrict__ bm,
                                                   const float* __restrict__ W1,
                                                   const float* __restrict__ b1,
                                                   const float* __restrict__ W2,
                                                   float* __restrict__ Mt,
                                                   int* __restrict__ gcur,
                                                   int* __restrict__ ovfn) {
    const int j = threadIdx.x;
    for (int i = j; i < NBUCK; i += 128) gcur[i] = 0;
    if (j == 0) *ovfn = 0;

    float w1c[128];
#pragma unroll
    for (int k = 0; k < 128; k++) w1c[k] = W1[k * 128 + j];

    float* row = Mt + j * 24;
#pragma unroll
    for (int m = 0; m < 3; m++) {
        float acc = 0.f;
#pragma unroll
        for (int k = 0; k < 64; k++) acc = fmaf(Wu[m * 64 + k], w1c[k], acc);
        row[m] = acc;
    }
#pragma unroll
    for (int m = 0; m < 18; m++) {
        float acc = 0.f;
#pragma unroll
        for (int k = 0; k < 64; k++) acc = fmaf(Wm[m * 64 + k], w1c[64 + k], acc);
        row[3 + m] = acc;
    }
    float bp = b1[j];
#pragma unroll
    for (int k = 0; k < 64; k++) {
        bp = fmaf(bu[k], w1c[k], bp);
        bp = fmaf(bm[k], w1c[64 + k], bp);
    }
    row[21] = bp;
    row[22] = W2[j];
    row[23] = 0.f;
}

// ---------------------------------------------------------------------------
// K_c: scatter into STATIC-STRIDE bucket runs (mid[b*CAP + pos]); no global
// scan needed. Single edge read pass (register staging), per-(block,bucket)
// reservation from gcur. Overflow (pos>=CAP) -> global ovf list (never on
// this input; correctness fallback).
// Payload: x = (col&127) | (row<<7), y = ew bits.
// ---------------------------------------------------------------------------
__global__ __launch_bounds__(256) void bscatter_kernel(const int* __restrict__ ei,
                                                       const float* __restrict__ ew,
                                                       int* __restrict__ gcur,
                                                       int2* __restrict__ mid,
                                                       int4* __restrict__ ovf,
                                                       int* __restrict__ ovfn) {
    __shared__ int h[NBUCK];
    __shared__ int rbase[NBUCK];
    int cs[SITER], rs[SITER];
    float wv[SITER];
    const int e0 = blockIdx.x * 256 + threadIdx.x;

    for (int i = threadIdx.x; i < NBUCK; i += 256) h[i] = 0;
    __syncthreads();
#pragma unroll
    for (int k = 0; k < SITER; k++) {
        const int e = e0 + k * (SBLK * 256);
        if (e < NE) {
            cs[k] = ei[NE + e];
            rs[k] = ei[e];
            wv[k] = ew[e];
            atomicAdd(&h[cs[k] >> BSH], 1);
        }
    }
    __syncthreads();
    for (int i = threadIdx.x; i < NBUCK; i += 256) {
        const int c0 = h[i];
        rbase[i] = c0 ? atomicAdd(&gcur[i], c0) : 0;
        h[i] = 0;   // reuse as running counter
    }
    __syncthreads();
#pragma unroll
    for (int k = 0; k < SITER; k++) {
        const int e = e0 + k * (SBLK * 256);
        if (e < NE) {
            const int bb = cs[k] >> BSH;
            const int pos = rbase[bb] + atomicAdd(&h[bb], 1);
            if (pos < CAP) {
                mid[(size_t)bb * CAP + pos] =
                    make_int2((cs[k] & (BCOLS - 1)) | (rs[k] << BSH),
                              __float_as_int(wv[k]));
            } else {
                const int oi = atomicAdd(ovfn, 1);
                if (oi < OVCAP)
                    ovf[oi] = make_int4(cs[k], rs[k], __float_as_int(wv[k]), 0);
            }
        }
    }
}

// ---------------------------------------------------------------------------
// K_d: fused per-bucket degree + fp16 row packing (rows 32 halves = 64 B).
// dinv kept fp32 for the exact epilogue scale. Reads its static-stride run.
// ---------------------------------------------------------------------------
__global__ __launch_bounds__(256) void bdeg_pack_kernel(const int2* __restrict__ mid,
                                                        const int* __restrict__ gcur,
                                                        const int* __restrict__ ovfn,
                                                        const int4* __restrict__ ovf,
                                                        const float* __restrict__ ux,
                                                        const float* __restrict__ mx,
                                                        unsigned short* __restrict__ pack16,
                                                        float* __restrict__ dinv) {
    __shared__ float dl[BCOLS];
    const int b = blockIdx.x;
    const int t = threadIdx.x;
    if (t < BCOLS) dl[t] = 0.f;
    __syncthreads();
    const int cntt = gcur[b];
    const int segc = cntt < CAP ? cntt : CAP;
    const int start = b * CAP;
    for (int i = t; i < segc; i += 256) {
        const int2 p = mid[start + i];
        atomicAdd(&dl[p.x & (BCOLS - 1)], __int_as_float(p.y));
    }
    if (cntt > CAP) {   // overflow fallback (never on this input)
        const int n = min(*ovfn, OVCAP);
        for (int i = t; i < n; i += 256) {
            const int4 q = ovf[i];
            if ((q.x >> BSH) == b)
                atomicAdd(&dl[q.x & (BCOLS - 1)], __int_as_float(q.z));
        }
    }
    __syncthreads();
    if (t < BCOLS) {
        const int r = b * BCOLS + t;
        if (r < NN) {
            const float d = rsqrtf(dl[t] + 1.0f);
            dinv[r] = d;
            float v[22];
            const float* u = ux + (size_t)r * 3;
            const float* m = mx + (size_t)r * 18;
            v[0] = d * u[0];
            v[1] = d * u[1];
            v[2] = d * u[2];
#pragma unroll
            for (int k = 0; k < 18; k++) v[3 + k] = d * m[k];
            v[21] = d;
            unsigned wb[16];
#pragma unroll
            for (int k = 0; k < 11; k++) wb[k] = f2h2(v[2 * k], v[2 * k + 1]);
#pragma unroll
            for (int k = 11; k < 16; k++) wb[k] = 0u;
            uint4* dst = (uint4*)(pack16 + (size_t)r * 32);
            dst[0] = make_uint4(wb[0], wb[1], wb[2], wb[3]);
            dst[1] = make_uint4(wb[4], wb[5], wb[6], wb[7]);
            dst[2] = make_uint4(wb[8], wb[9], wb[10], wb[11]);
            dst[3] = make_uint4(wb[12], wb[13], wb[14], wb[15]);
        }
    }
}

// ---------------------------------------------------------------------------
// K_e: 512 threads / bucket, 4 wave-adjacent lanes per col (col=t>>2,
// sub=t&3). Counting sort into LDS as proven; combines are pure shfl_xor
// (no sp/po LDS, 4 fewer barriers); per-lane gather chain ~2.5; MLP k-split
// 4-way (32 k's per lane). ~24 waves/CU vs 12 before.
// ---------------------------------------------------------------------------
__global__ __launch_bounds__(512) void bagg_mlp_kernel(const int2* __restrict__ mid,
                                                       const int* __restrict__ gcur,
                                                       const int* __restrict__ ovfn,
                                                       const int4* __restrict__ ovf,
                                                       const unsigned short* __restrict__ pack16,
                                                       const float* __restrict__ dinv,
                                                       const float* __restrict__ Mt,
                                                       const float* __restrict__ b2,
                                                       float* __restrict__ out) {
    __shared__ int2 smid[CAP];          // 16 KB: sorted payloads
    __shared__ int ccnt[BCOLS];         // per-col counts
    __shared__ int cbase[BCOLS];        // inclusive scan
    __shared__ int cptr[BCOLS];         // running scatter pointers

    const int b = blockIdx.x;
    const int t = threadIdx.x;
    const int col = t >> 2;
    const int sub = t & 3;
    const int start = b * CAP;
    const int cntt = gcur[b];
    const int segc = cntt < CAP ? cntt : CAP;

    // phase 1: per-col counts (coalesced mid read #1)
    if (t < BCOLS) ccnt[t] = 0;
    __syncthreads();
    for (int i = t; i < segc; i += 512)
        atomicAdd(&ccnt[mid[start + i].x & (BCOLS - 1)], 1);
    __syncthreads();

    // phase 2: wave 0 scans the 128 counts (2 per lane, shfl_up)
    if (t < 64) {
        const int a = ccnt[2 * t];
        const int bb = ccnt[2 * t + 1];
        int p = a + bb;
#pragma unroll
        for (int d = 1; d < 64; d <<= 1) {
            const int x = __shfl_up(p, d, 64);
            if (t >= d) p += x;
        }
        cbase[2 * t] = p - bb;          // inclusive
        cbase[2 * t + 1] = p;
        cptr[2 * t] = p - bb - a;       // exclusive = scatter base
        cptr[2 * t + 1] = p - bb;
    }
    __syncthreads();

    // phase 3: scatter payloads into LDS sorted order (mid read #2, L2-hot)
    for (int i = t; i < segc; i += 512) {
        const int2 p = mid[start + i];
        const int pos = atomicAdd(&cptr[p.x & (BCOLS - 1)], 1);
        smid[pos] = p;
    }
    __syncthreads();

    // phase 4: register aggregation, 4 wave-adjacent lanes per col
    float s21[21];
#pragma unroll
    for (int m = 0; m < 21; m++) s21[m] = 0.f;

    const int s0 = (col == 0) ? 0 : cbase[col - 1];
    const int s1 = cbase[col];
#pragma unroll 2
    for (int i = s0 + sub; i < s1; i += 4) {
        const int2 p = smid[i];
        const unsigned row = ((unsigned)p.x) >> BSH;
        const float w = __int_as_float(p.y);
        ACC_ROW16(pack16 + (size_t)row * 32);
    }

    const int c = b * BCOLS + col;
    // overflow fallback (never on this input) -- BEFORE the quad combine
    if (cntt > CAP && sub == 0 && c < NN) {
        const int n = min(*ovfn, OVCAP);
        for (int i = 0; i < n; i++) {
            const int4 q = ovf[i];
            if (q.x == c) {
                const unsigned row = (unsigned)q.y;
                const float w = __int_as_float(q.z);
                ACC_ROW16(pack16 + (size_t)row * 32);
            }
        }
    }

    // quad combine: all 4 lanes end with the full edge sum
#pragma unroll
    for (int m = 0; m < 21; m++) {
        s21[m] += __shfl_xor(s21[m], 1);
        s21[m] += __shfl_xor(s21[m], 2);
    }

    float o = 0.f;
    if (c < NN) {
        // self-loop (pack row already dinv-scaled; same line for all 4 lanes)
        const float w = 1.0f;
        ACC_ROW16(pack16 + (size_t)c * 32);
        const float d = dinv[c];
#pragma unroll
        for (int m = 0; m < 21; m++) s21[m] *= d;

        // fused MLP: 32 hidden units per sub-lane (Mt 12 KB, L1-hot)
        const int k0 = sub * 32;
#pragma unroll 2
        for (int k = k0; k < k0 + 32; k++) {
            const float* r = Mt + k * 24;
            float hsum = r[21];
#pragma unroll
            for (int m = 0; m < 21; m++) hsum = fmaf(s21[m], r[m], hsum);
            o = fmaf(fmaxf(hsum, 0.f), r[22], o);
        }
    }
    o += __shfl_xor(o, 1);
    o += __shfl_xor(o, 2);
    if (sub == 0 && c < NN) out[c] = o + b2[0];
}

// ===========================================================================
extern "C" void kernel_launch(void* const* d_in, const int* in_sizes, int n_in,
                              void* d_out, int out_size, void* d_ws, size_t ws_size,
                              hipStream_t stream) {
    const float* ux = (const float*)d_in[0];   // user_x  [N,3]
    const float* mx = (const float*)d_in[1];   // movie_x [N,18]
    const int* ei = (const int*)d_in[2];       // edge_index [2,E]
    const float* ew = (const float*)d_in[3];   // edge_attr [E]
    const float* Wu = (const float*)d_in[4];   // [3,64]
    const float* bu = (const float*)d_in[5];   // [64]
    const float* Wm = (const float*)d_in[6];   // [18,64]
    const float* bm = (const float*)d_in[7];   // [64]
    const float* W1 = (const float*)d_in[8];   // [128,128]
    const float* b1 = (const float*)d_in[9];   // [128]
    const float* W2 = (const float*)d_in[10];  // [128,1]
    const float* b2 = (const float*)d_in[11];  // [1]
    float* out = (float*)d_out;

    char* ws = (char*)d_ws;
    int*            gcur   = (int*)ws;                      // @0         3,128 B
    int*            ovfn   = (int*)(ws + 4096);             // @4096      4 B
    float*          Mt     = (float*)(ws + 8192);           // @8192      12,288 B
    float*          dinv   = (float*)(ws + 20480);          // @20480     400,000 B
    unsigned short* pack16 = (unsigned short*)(ws + 420480);// @420480    6,400,000 B (64B-aligned)
    int2*           mid    = (int2*)(ws + 6820480);         // @6820480   12,812,288 B (64B-aligned)
    int4*           ovf    = (int4*)(ws + 19632768);        // @19632768  262,144 B
    // total ~19.9 MB

    fuse_kernel<<<1, 128, 0, stream>>>(Wu, bu, Wm, bm, W1, b1, W2, Mt, gcur, ovfn);
    bscatter_kernel<<<SBLK, 256, 0, stream>>>(ei, ew, gcur, mid, ovf, ovfn);
    bdeg_pack_kernel<<<NBUCK, 256, 0, stream>>>(mid, gcur, ovfn, ovf, ux, mx, pack16, dinv);
    bagg_mlp_kernel<<<NBUCK, 512, 0, stream>>>(mid, gcur, ovfn, ovf, pack16, dinv, Mt, b2, out);
}

// Round 9
// 185.734 us; speedup vs baseline: 1.6809x; 1.6809x over previous
//
#include <hip/hip_runtime.h>
#include <hip/hip_fp16.h>

#define NN 100000
#define NE 1000000
#define BSH 7        // bucket shift: 128 cols per bucket
#define BCOLS 128
#define NBUCK 782    // ceil(NN / 128)
#define SBLK 256     // edge-partition blocks for scatter (proven best)
#define SITER 16     // edges per scatter thread
#define CAP 2048     // static per-bucket stride in mid (mean 1279, sd ~36: 21 sigma)
#define OVCAP 16384  // overflow list capacity (statistically never used)

// fp16 helpers -------------------------------------------------------------
__device__ __forceinline__ float2 h2f(unsigned u) {
    union { unsigned u; __half2 h; } c; c.u = u;
    return __half22float2(c.h);
}
__device__ __forceinline__ unsigned f2h2(float a, float b) {
    union { __half2 h; unsigned u; } c; c.h = __floats2half2_rn(a, b);
    return c.u;
}

// fp16 row accumulate: s21 += w * pack16row (3 independent 16B loads) --------
#define ACC_ROW16(base)                                                      \
    {                                                                        \
        const uint4* pr_ = (const uint4*)(base);                             \
        const uint4 A_ = pr_[0];                                             \
        const uint4 B_ = pr_[1];                                             \
        const uint4 C_ = pr_[2];                                             \
        float2 f_;                                                           \
        f_ = h2f(A_.x); s21[0]  = fmaf(w, f_.x, s21[0]);  s21[1]  = fmaf(w, f_.y, s21[1]);  \
        f_ = h2f(A_.y); s21[2]  = fmaf(w, f_.x, s21[2]);  s21[3]  = fmaf(w, f_.y, s21[3]);  \
        f_ = h2f(A_.z); s21[4]  = fmaf(w, f_.x, s21[4]);  s21[5]  = fmaf(w, f_.y, s21[5]);  \
        f_ = h2f(A_.w); s21[6]  = fmaf(w, f_.x, s21[6]);  s21[7]  = fmaf(w, f_.y, s21[7]);  \
        f_ = h2f(B_.x); s21[8]  = fmaf(w, f_.x, s21[8]);  s21[9]  = fmaf(w, f_.y, s21[9]);  \
        f_ = h2f(B_.y); s21[10] = fmaf(w, f_.x, s21[10]); s21[11] = fmaf(w, f_.y, s21[11]); \
        f_ = h2f(B_.z); s21[12] = fmaf(w, f_.x, s21[12]); s21[13] = fmaf(w, f_.y, s21[13]); \
        f_ = h2f(B_.w); s21[14] = fmaf(w, f_.x, s21[14]); s21[15] = fmaf(w, f_.y, s21[15]); \
        f_ = h2f(C_.x); s21[16] = fmaf(w, f_.x, s21[16]); s21[17] = fmaf(w, f_.y, s21[17]); \
        f_ = h2f(C_.y); s21[18] = fmaf(w, f_.x, s21[18]); s21[19] = fmaf(w, f_.y, s21[19]); \
        f_ = h2f(C_.z); s21[20] = fmaf(w, f_.x, s21[20]);                    \
    }

// ---------------------------------------------------------------------------
// K_f: fuse the whole linear chain into Mt[128][24]; zeroes gcur[NBUCK]+ovfn.
// ---------------------------------------------------------------------------
__global__ __launch_bounds__(128) void fuse_kernel(const float* __restrict__ Wu,
                                                   const float* __restrict__ bu,
                                                   const float* __restrict__ Wm,
                                                   const float* __restrict__ bm,
                                                   const float* __restrict__ W1,
                                                   const float* __restrict__ b1,
                                                   const float* __restrict__ W2,
                                                   float* __restrict__ Mt,
                                                   int* __restrict__ gcur,
                                                   int* __restrict__ ovfn) {
    const int j = threadIdx.x;
    for (int i = j; i < NBUCK; i += 128) gcur[i] = 0;
    if (j == 0) *ovfn = 0;

    float w1c[128];
#pragma unroll
    for (int k = 0; k < 128; k++) w1c[k] = W1[k * 128 + j];

    float* row = Mt + j * 24;
#pragma unroll
    for (int m = 0; m < 3; m++) {
        float acc = 0.f;
#pragma unroll
        for (int k = 0; k < 64; k++) acc = fmaf(Wu[m * 64 + k], w1c[k], acc);
        row[m] = acc;
    }
#pragma unroll
    for (int m = 0; m < 18; m++) {
        float acc = 0.f;
#pragma unroll
        for (int k = 0; k < 64; k++) acc = fmaf(Wm[m * 64 + k], w1c[64 + k], acc);
        row[3 + m] = acc;
    }
    float bp = b1[j];
#pragma unroll
    for (int k = 0; k < 64; k++) {
        bp = fmaf(bu[k], w1c[k], bp);
        bp = fmaf(bm[k], w1c[64 + k], bp);
    }
    row[21] = bp;
    row[22] = W2[j];
    row[23] = 0.f;
}

// ---------------------------------------------------------------------------
// K_c: scatter into STATIC-STRIDE bucket runs (mid[b*CAP + pos]); no global
// scan. Single edge read pass (register staging), per-(block,bucket)
// reservation from gcur. Overflow (pos>=CAP) -> global ovf list (never on
// this input; correctness fallback).
// Payload: x = (col&127) | (row<<7), y = ew bits.
// ---------------------------------------------------------------------------
__global__ __launch_bounds__(256) void bscatter_kernel(const int* __restrict__ ei,
                                                       const float* __restrict__ ew,
                                                       int* __restrict__ gcur,
                                                       int2* __restrict__ mid,
                                                       int4* __restrict__ ovf,
                                                       int* __restrict__ ovfn) {
    __shared__ int h[NBUCK];
    __shared__ int rbase[NBUCK];
    int cs[SITER], rs[SITER];
    float wv[SITER];
    const int e0 = blockIdx.x * 256 + threadIdx.x;

    for (int i = threadIdx.x; i < NBUCK; i += 256) h[i] = 0;
    __syncthreads();
#pragma unroll
    for (int k = 0; k < SITER; k++) {
        const int e = e0 + k * (SBLK * 256);
        if (e < NE) {
            cs[k] = ei[NE + e];
            rs[k] = ei[e];
            wv[k] = ew[e];
            atomicAdd(&h[cs[k] >> BSH], 1);
        }
    }
    __syncthreads();
    for (int i = threadIdx.x; i < NBUCK; i += 256) {
        const int c0 = h[i];
        rbase[i] = c0 ? atomicAdd(&gcur[i], c0) : 0;
        h[i] = 0;   // reuse as running counter
    }
    __syncthreads();
#pragma unroll
    for (int k = 0; k < SITER; k++) {
        const int e = e0 + k * (SBLK * 256);
        if (e < NE) {
            const int bb = cs[k] >> BSH;
            const int pos = rbase[bb] + atomicAdd(&h[bb], 1);
            if (pos < CAP) {
                mid[(size_t)bb * CAP + pos] =
                    make_int2((cs[k] & (BCOLS - 1)) | (rs[k] << BSH),
                              __float_as_int(wv[k]));
            } else {
                const int oi = atomicAdd(ovfn, 1);
                if (oi < OVCAP)
                    ovf[oi] = make_int4(cs[k], rs[k], __float_as_int(wv[k]), 0);
            }
        }
    }
}

// ---------------------------------------------------------------------------
// K_d: fused per-bucket degree + fp16 row packing (rows 32 halves = 64 B).
// dinv kept fp32 for the exact epilogue scale. Reads its static-stride run.
// ---------------------------------------------------------------------------
__global__ __launch_bounds__(256) void bdeg_pack_kernel(const int2* __restrict__ mid,
                                                        const int* __restrict__ gcur,
                                                        const int* __restrict__ ovfn,
                                                        const int4* __restrict__ ovf,
                                                        const float* __restrict__ ux,
                                                        const float* __restrict__ mx,
                                                        unsigned short* __restrict__ pack16,
                                                        float* __restrict__ dinv) {
    __shared__ float dl[BCOLS];
    const int b = blockIdx.x;
    const int t = threadIdx.x;
    if (t < BCOLS) dl[t] = 0.f;
    __syncthreads();
    const int cntt = gcur[b];
    const int segc = cntt < CAP ? cntt : CAP;
    const int start = b * CAP;
    for (int i = t; i < segc; i += 256) {
        const int2 p = mid[start + i];
        atomicAdd(&dl[p.x & (BCOLS - 1)], __int_as_float(p.y));
    }
    if (cntt > CAP) {   // overflow fallback (never on this input)
        const int n = min(*ovfn, OVCAP);
        for (int i = t; i < n; i += 256) {
            const int4 q = ovf[i];
            if ((q.x >> BSH) == b)
                atomicAdd(&dl[q.x & (BCOLS - 1)], __int_as_float(q.z));
        }
    }
    __syncthreads();
    if (t < BCOLS) {
        const int r = b * BCOLS + t;
        if (r < NN) {
            const float d = rsqrtf(dl[t] + 1.0f);
            dinv[r] = d;
            float v[22];
            const float* u = ux + (size_t)r * 3;
            const float* m = mx + (size_t)r * 18;
            v[0] = d * u[0];
            v[1] = d * u[1];
            v[2] = d * u[2];
#pragma unroll
            for (int k = 0; k < 18; k++) v[3 + k] = d * m[k];
            v[21] = d;
            unsigned wb[16];
#pragma unroll
            for (int k = 0; k < 11; k++) wb[k] = f2h2(v[2 * k], v[2 * k + 1]);
#pragma unroll
            for (int k = 11; k < 16; k++) wb[k] = 0u;
            uint4* dst = (uint4*)(pack16 + (size_t)r * 32);
            dst[0] = make_uint4(wb[0], wb[1], wb[2], wb[3]);
            dst[1] = make_uint4(wb[4], wb[5], wb[6], wb[7]);
            dst[2] = make_uint4(wb[8], wb[9], wb[10], wb[11]);
            dst[3] = make_uint4(wb[12], wb[13], wb[14], wb[15]);
        }
    }
}

// ---------------------------------------------------------------------------
// K_e: 512 threads / bucket, 4 WAVE-UNIFORM quarters per col: col = t&127,
// hf = t>>7 in {0..3} (each quarter = 2 waves). Counting sort into LDS as
// proven; quarter partials combined via LDS slabs (1 barrier); MLP k-split
// 4-way with k0 = hf*32 -> Mt loads stay wave-uniform SCALAR loads (the
// round-8 regression was lane-varying Mt addressing).
// ---------------------------------------------------------------------------
__global__ __launch_bounds__(512) void bagg_mlp_kernel(const int2* __restrict__ mid,
                                                       const int* __restrict__ gcur,
                                                       const int* __restrict__ ovfn,
                                                       const int4* __restrict__ ovf,
                                                       const unsigned short* __restrict__ pack16,
                                                       const float* __restrict__ dinv,
                                                       const float* __restrict__ Mt,
                                                       const float* __restrict__ b2,
                                                       float* __restrict__ out) {
    __shared__ int2 smid[CAP];          // 16 KB: sorted payloads
    __shared__ int ccnt[BCOLS];         // per-col counts
    __shared__ int cbase[BCOLS];        // inclusive scan
    __shared__ int cptr[BCOLS];         // running scatter pointers
    __shared__ float sp[3][BCOLS][21];  // 31.5 KB: quarter partials / final s21
    __shared__ float po[3][BCOLS];      // 1.5 KB: MLP quarter partials

    const int b = blockIdx.x;
    const int t = threadIdx.x;
    const int col = t & (BCOLS - 1);
    const int hf = t >> 7;              // 0..3, wave-uniform
    const int start = b * CAP;
    const int cntt = gcur[b];
    const int segc = cntt < CAP ? cntt : CAP;

    // phase 1: per-col counts (coalesced mid read #1)
    if (t < BCOLS) ccnt[t] = 0;
    __syncthreads();
    for (int i = t; i < segc; i += 512)
        atomicAdd(&ccnt[mid[start + i].x & (BCOLS - 1)], 1);
    __syncthreads();

    // phase 2: wave 0 scans the 128 counts (2 per lane, shfl_up)
    if (t < 64) {
        const int a = ccnt[2 * t];
        const int bb = ccnt[2 * t + 1];
        int p = a + bb;
#pragma unroll
        for (int d = 1; d < 64; d <<= 1) {
            const int x = __shfl_up(p, d, 64);
            if (t >= d) p += x;
        }
        cbase[2 * t] = p - bb;          // inclusive
        cbase[2 * t + 1] = p;
        cptr[2 * t] = p - bb - a;       // exclusive = scatter base
        cptr[2 * t + 1] = p - bb;
    }
    __syncthreads();

    // phase 3: scatter payloads into LDS sorted order (mid read #2, L2-hot)
    for (int i = t; i < segc; i += 512) {
        const int2 p = mid[start + i];
        const int pos = atomicAdd(&cptr[p.x & (BCOLS - 1)], 1);
        smid[pos] = p;
    }
    __syncthreads();

    // phase 4: register aggregation, 4 wave-uniform quarters per col
    float s21[21];
#pragma unroll
    for (int m = 0; m < 21; m++) s21[m] = 0.f;

    const int s0 = (col == 0) ? 0 : cbase[col - 1];
    const int s1 = cbase[col];
#pragma unroll 2
    for (int i = s0 + hf; i < s1; i += 4) {
        const int2 p = smid[i];
        const unsigned row = ((unsigned)p.x) >> BSH;
        const float w = __int_as_float(p.y);
        ACC_ROW16(pack16 + (size_t)row * 32);
    }

    // combine quarters: 1..3 publish, quarter 0 owns the column
    if (hf) {
#pragma unroll
        for (int m = 0; m < 21; m++) sp[hf - 1][col][m] = s21[m];
    }
    __syncthreads();

    const int c = b * BCOLS + col;
    if (hf == 0) {
#pragma unroll
        for (int m = 0; m < 21; m++)
            s21[m] += sp[0][col][m] + sp[1][col][m] + sp[2][col][m];
        // overflow fallback (never on this input)
        if (cntt > CAP && c < NN) {
            const int n = min(*ovfn, OVCAP);
            for (int i = 0; i < n; i++) {
                const int4 q = ovf[i];
                if (q.x == c) {
                    const unsigned row = (unsigned)q.y;
                    const float w = __int_as_float(q.z);
                    ACC_ROW16(pack16 + (size_t)row * 32);
                }
            }
        }
        if (c < NN) {
            // self-loop (pack row already dinv-scaled) + exact fp32 dinv[c]
            const float w = 1.0f;
            ACC_ROW16(pack16 + (size_t)c * 32);
            const float d = dinv[c];
#pragma unroll
            for (int m = 0; m < 21; m++) s21[m] *= d;
        }
        // publish final s21 for quarters 1..3
#pragma unroll
        for (int m = 0; m < 21; m++) sp[0][col][m] = s21[m];
    }
    __syncthreads();
    if (hf) {
#pragma unroll
        for (int m = 0; m < 21; m++) s21[m] = sp[0][col][m];
    }

    // fused MLP: 32 hidden units per quarter, k0 wave-uniform -> scalar Mt
    float o = 0.f;
    if (c < NN) {
        const int k0 = hf * 32;
#pragma unroll 2
        for (int k = k0; k < k0 + 32; k++) {
            const float* r = Mt + k * 24;
            float hsum = r[21];
#pragma unroll
            for (int m = 0; m < 21; m++) hsum = fmaf(s21[m], r[m], hsum);
            o = fmaf(fmaxf(hsum, 0.f), r[22], o);
        }
    }
    if (hf) po[hf - 1][col] = o;
    __syncthreads();
    if (hf == 0 && c < NN)
        out[c] = o + po[0][col] + po[1][col] + po[2][col] + b2[0];
}

// ===========================================================================
extern "C" void kernel_launch(void* const* d_in, const int* in_sizes, int n_in,
                              void* d_out, int out_size, void* d_ws, size_t ws_size,
                              hipStream_t stream) {
    const float* ux = (const float*)d_in[0];   // user_x  [N,3]
    const float* mx = (const float*)d_in[1];   // movie_x [N,18]
    const int* ei = (const int*)d_in[2];       // edge_index [2,E]
    const float* ew = (const float*)d_in[3];   // edge_attr [E]
    const float* Wu = (const float*)d_in[4];   // [3,64]
    const float* bu = (const float*)d_in[5];   // [64]
    const float* Wm = (const float*)d_in[6];   // [18,64]
    const float* bm = (const float*)d_in[7];   // [64]
    const float* W1 = (const float*)d_in[8];   // [128,128]
    const float* b1 = (const float*)d_in[9];   // [128]
    const float* W2 = (const float*)d_in[10];  // [128,1]
    const float* b2 = (const float*)d_in[11];  // [1]
    float* out = (float*)d_out;

    char* ws = (char*)d_ws;
    int*            gcur   = (int*)ws;                      // @0         3,128 B
    int*            ovfn   = (int*)(ws + 4096);             // @4096      4 B
    float*          Mt     = (float*)(ws + 8192);           // @8192      12,288 B
    float*          dinv   = (float*)(ws + 20480);          // @20480     400,000 B
    unsigned short* pack16 = (unsigned short*)(ws + 420480);// @420480    6,400,000 B (64B-aligned)
    int2*           mid    = (int2*)(ws + 6820480);         // @6820480   12,812,288 B (64B-aligned)
    int4*           ovf    = (int4*)(ws + 19632768);        // @19632768  262,144 B
    // total ~19.9 MB

    fuse_kernel<<<1, 128, 0, stream>>>(Wu, bu, Wm, bm, W1, b1, W2, Mt, gcur, ovfn);
    bscatter_kernel<<<SBLK, 256, 0, stream>>>(ei, ew, gcur, mid, ovf, ovfn);
    bdeg_pack_kernel<<<NBUCK, 256, 0, stream>>>(mid, gcur, ovfn, ovf, ux, mx, pack16, dinv);
    bagg_mlp_kernel<<<NBUCK, 512, 0, stream>>>(mid, gcur, ovfn, ovf, pack16, dinv, Mt, b2, out);
}

// Round 10
// 181.617 us; speedup vs baseline: 1.7190x; 1.0227x over previous
//
#include <hip/hip_runtime.h>
#include <hip/hip_fp16.h>

#define NN 100000
#define NE 1000000
#define BSH 7        // bucket shift: 128 cols per bucket
#define BCOLS 128
#define NBUCK 782    // ceil(NN / 128)
#define SBLK 256     // edge-partition blocks for scatter (proven best)
#define SITER 16     // edges per scatter thread
#define CAP 2048     // static per-bucket stride in mid (mean 1279, sd ~36: 21 sigma)
#define OVCAP 16384  // overflow list capacity (statistically never used)

// fp16 helpers -------------------------------------------------------------
__device__ __forceinline__ float2 h2f(unsigned u) {
    union { unsigned u; __half2 h; } c; c.u = u;
    return __half22float2(c.h);
}
__device__ __forceinline__ unsigned f2h2(float a, float b) {
    union { __half2 h; unsigned u; } c; c.h = __floats2half2_rn(a, b);
    return c.u;
}

// fp16 full-row accumulate (epilogue/overflow only): s21 += w * pack16row ----
#define ACC_ROW16(base)                                                      \
    {                                                                        \
        const uint4* pr_ = (const uint4*)(base);                             \
        const uint4 A_ = pr_[0];                                             \
        const uint4 B_ = pr_[1];                                             \
        const uint4 C_ = pr_[2];                                             \
        float2 f_;                                                           \
        f_ = h2f(A_.x); s21[0]  = fmaf(w, f_.x, s21[0]);  s21[1]  = fmaf(w, f_.y, s21[1]);  \
        f_ = h2f(A_.y); s21[2]  = fmaf(w, f_.x, s21[2]);  s21[3]  = fmaf(w, f_.y, s21[3]);  \
        f_ = h2f(A_.z); s21[4]  = fmaf(w, f_.x, s21[4]);  s21[5]  = fmaf(w, f_.y, s21[5]);  \
        f_ = h2f(A_.w); s21[6]  = fmaf(w, f_.x, s21[6]);  s21[7]  = fmaf(w, f_.y, s21[7]);  \
        f_ = h2f(B_.x); s21[8]  = fmaf(w, f_.x, s21[8]);  s21[9]  = fmaf(w, f_.y, s21[9]);  \
        f_ = h2f(B_.y); s21[10] = fmaf(w, f_.x, s21[10]); s21[11] = fmaf(w, f_.y, s21[11]); \
        f_ = h2f(B_.z); s21[12] = fmaf(w, f_.x, s21[12]); s21[13] = fmaf(w, f_.y, s21[13]); \
        f_ = h2f(B_.w); s21[14] = fmaf(w, f_.x, s21[14]); s21[15] = fmaf(w, f_.y, s21[15]); \
        f_ = h2f(C_.x); s21[16] = fmaf(w, f_.x, s21[16]); s21[17] = fmaf(w, f_.y, s21[17]); \
        f_ = h2f(C_.y); s21[18] = fmaf(w, f_.x, s21[18]); s21[19] = fmaf(w, f_.y, s21[19]); \
        f_ = h2f(C_.z); s21[20] = fmaf(w, f_.x, s21[20]);                    \
    }

// ---------------------------------------------------------------------------
// K_f: fuse the whole linear chain into Mt[128][24]; zeroes gcur[NBUCK]+ovfn.
// ---------------------------------------------------------------------------
__global__ __launch_bounds__(128) void fuse_kernel(const float* __restrict__ Wu,
                                                   const float* __restrict__ bu,
                                                   const float* __restrict__ Wm,
                                                   const float* __restrict__ bm,
                                                   const float* __restrict__ W1,
                                                   const float* __restrict__ b1,
                                                   const float* __restrict__ W2,
                                                   float* __restrict__ Mt,
                                                   int* __restrict__ gcur,
                                                   int* __restrict__ ovfn) {
    const int j = threadIdx.x;
    for (int i = j; i < NBUCK; i += 128) gcur[i] = 0;
    if (j == 0) *ovfn = 0;

    float w1c[128];
#pragma unroll
    for (int k = 0; k < 128; k++) w1c[k] = W1[k * 128 + j];

    float* row = Mt + j * 24;
#pragma unroll
    for (int m = 0; m < 3; m++) {
        float acc = 0.f;
#pragma unroll
        for (int k = 0; k < 64; k++) acc = fmaf(Wu[m * 64 + k], w1c[k], acc);
        row[m] = acc;
    }
#pragma unroll
    for (int m = 0; m < 18; m++) {
        float acc = 0.f;
#pragma unroll
        for (int k = 0; k < 64; k++) acc = fmaf(Wm[m * 64 + k], w1c[64 + k], acc);
        row[3 + m] = acc;
    }
    float bp = b1[j];
#pragma unroll
    for (int k = 0; k < 64; k++) {
        bp = fmaf(bu[k], w1c[k], bp);
        bp = fmaf(bm[k], w1c[64 + k], bp);
    }
    row[21] = bp;
    row[22] = W2[j];
    row[23] = 0.f;
}

// ---------------------------------------------------------------------------
// K_c: scatter into STATIC-STRIDE bucket runs (mid[b*CAP + pos]); no global
// scan. Single edge read pass (register staging), per-(block,bucket)
// reservation from gcur. Overflow (pos>=CAP) -> global ovf list (never on
// this input; correctness fallback).
// Payload: x = (col&127) | (row<<7), y = ew bits.
// ---------------------------------------------------------------------------
__global__ __launch_bounds__(256) void bscatter_kernel(const int* __restrict__ ei,
                                                       const float* __restrict__ ew,
                                                       int* __restrict__ gcur,
                                                       int2* __restrict__ mid,
                                                       int4* __restrict__ ovf,
                                                       int* __restrict__ ovfn) {
    __shared__ int h[NBUCK];
    __shared__ int rbase[NBUCK];
    int cs[SITER], rs[SITER];
    float wv[SITER];
    const int e0 = blockIdx.x * 256 + threadIdx.x;

    for (int i = threadIdx.x; i < NBUCK; i += 256) h[i] = 0;
    __syncthreads();
#pragma unroll
    for (int k = 0; k < SITER; k++) {
        const int e = e0 + k * (SBLK * 256);
        if (e < NE) {
            cs[k] = ei[NE + e];
            rs[k] = ei[e];
            wv[k] = ew[e];
            atomicAdd(&h[cs[k] >> BSH], 1);
        }
    }
    __syncthreads();
    for (int i = threadIdx.x; i < NBUCK; i += 256) {
        const int c0 = h[i];
        rbase[i] = c0 ? atomicAdd(&gcur[i], c0) : 0;
        h[i] = 0;   // reuse as running counter
    }
    __syncthreads();
#pragma unroll
    for (int k = 0; k < SITER; k++) {
        const int e = e0 + k * (SBLK * 256);
        if (e < NE) {
            const int bb = cs[k] >> BSH;
            const int pos = rbase[bb] + atomicAdd(&h[bb], 1);
            if (pos < CAP) {
                mid[(size_t)bb * CAP + pos] =
                    make_int2((cs[k] & (BCOLS - 1)) | (rs[k] << BSH),
                              __float_as_int(wv[k]));
            } else {
                const int oi = atomicAdd(ovfn, 1);
                if (oi < OVCAP)
                    ovf[oi] = make_int4(cs[k], rs[k], __float_as_int(wv[k]), 0);
            }
        }
    }
}

// ---------------------------------------------------------------------------
// K_d: fused per-bucket degree + fp16 row packing (rows 32 halves = 64 B).
// dinv kept fp32 for the exact epilogue scale. Reads its static-stride run.
// ---------------------------------------------------------------------------
__global__ __launch_bounds__(256) void bdeg_pack_kernel(const int2* __restrict__ mid,
                                                        const int* __restrict__ gcur,
                                                        const int* __restrict__ ovfn,
                                                        const int4* __restrict__ ovf,
                                                        const float* __restrict__ ux,
                                                        const float* __restrict__ mx,
                                                        unsigned short* __restrict__ pack16,
                                                        float* __restrict__ dinv) {
    __shared__ float dl[BCOLS];
    const int b = blockIdx.x;
    const int t = threadIdx.x;
    if (t < BCOLS) dl[t] = 0.f;
    __syncthreads();
    const int cntt = gcur[b];
    const int segc = cntt < CAP ? cntt : CAP;
    const int start = b * CAP;
    for (int i = t; i < segc; i += 256) {
        const int2 p = mid[start + i];
        atomicAdd(&dl[p.x & (BCOLS - 1)], __int_as_float(p.y));
    }
    if (cntt > CAP) {   // overflow fallback (never on this input)
        const int n = min(*ovfn, OVCAP);
        for (int i = t; i < n; i += 256) {
            const int4 q = ovf[i];
            if ((q.x >> BSH) == b)
                atomicAdd(&dl[q.x & (BCOLS - 1)], __int_as_float(q.z));
        }
    }
    __syncthreads();
    if (t < BCOLS) {
        const int r = b * BCOLS + t;
        if (r < NN) {
            const float d = rsqrtf(dl[t] + 1.0f);
            dinv[r] = d;
            float v[22];
            const float* u = ux + (size_t)r * 3;
            const float* m = mx + (size_t)r * 18;
            v[0] = d * u[0];
            v[1] = d * u[1];
            v[2] = d * u[2];
#pragma unroll
            for (int k = 0; k < 18; k++) v[3 + k] = d * m[k];
            v[21] = d;
            unsigned wb[16];
#pragma unroll
            for (int k = 0; k < 11; k++) wb[k] = f2h2(v[2 * k], v[2 * k + 1]);
#pragma unroll
            for (int k = 11; k < 16; k++) wb[k] = 0u;
            uint4* dst = (uint4*)(pack16 + (size_t)r * 32);
            dst[0] = make_uint4(wb[0], wb[1], wb[2], wb[3]);
            dst[1] = make_uint4(wb[4], wb[5], wb[6], wb[7]);
            dst[2] = make_uint4(wb[8], wb[9], wb[10], wb[11]);
            dst[3] = make_uint4(wb[12], wb[13], wb[14], wb[15]);
        }
    }
}

// ---------------------------------------------------------------------------
// K_e: QUAD-SLICE gather. 512 threads: phase 4 uses (colq = t>>2, slice = t&3)
// -- the quad's 4 lanes load 4 consecutive 16B chunks of the SAME 64B pack
// row => 1 line transaction per edge (vs 64 distinct lines per wave-load
// before). Each lane accumulates a disjoint 8-feature slice over ALL of its
// column's edges (no reduction -- LDS placement into padded sfin[128][33]).
// Epilogue re-indexes (col = t&127, hf = t>>7, wave-uniform) -> Mt stays
// scalar-loaded (round-8 lesson).
// ---------------------------------------------------------------------------
__global__ __launch_bounds__(512) void bagg_mlp_kernel(const int2* __restrict__ mid,
                                                       const int* __restrict__ gcur,
                                                       const int* __restrict__ ovfn,
                                                       const int4* __restrict__ ovf,
                                                       const unsigned short* __restrict__ pack16,
                                                       const float* __restrict__ dinv,
                                                       const float* __restrict__ Mt,
                                                       const float* __restrict__ b2,
                                                       float* __restrict__ out) {
    __shared__ int2 smid[CAP];          // 16 KB: sorted payloads
    __shared__ int ccnt[BCOLS];         // per-col counts
    __shared__ int cbase[BCOLS];        // inclusive scan
    __shared__ int cptr[BCOLS];         // running scatter pointers
    __shared__ float sfin[BCOLS][33];   // 16.9 KB: sliced sums (33: pad vs bank conflicts)
    __shared__ float po[3][BCOLS];      // 1.5 KB: MLP quarter partials

    const int b = blockIdx.x;
    const int t = threadIdx.x;
    const int start = b * CAP;
    const int cntt = gcur[b];
    const int segc = cntt < CAP ? cntt : CAP;

    // phase 1: per-col counts (coalesced mid read #1)
    if (t < BCOLS) ccnt[t] = 0;
    __syncthreads();
    for (int i = t; i < segc; i += 512)
        atomicAdd(&ccnt[mid[start + i].x & (BCOLS - 1)], 1);
    __syncthreads();

    // phase 2: wave 0 scans the 128 counts (2 per lane, shfl_up)
    if (t < 64) {
        const int a = ccnt[2 * t];
        const int bb = ccnt[2 * t + 1];
        int p = a + bb;
#pragma unroll
        for (int d = 1; d < 64; d <<= 1) {
            const int x = __shfl_up(p, d, 64);
            if (t >= d) p += x;
        }
        cbase[2 * t] = p - bb;          // inclusive
        cbase[2 * t + 1] = p;
        cptr[2 * t] = p - bb - a;       // exclusive = scatter base
        cptr[2 * t + 1] = p - bb;
    }
    __syncthreads();

    // phase 3: scatter payloads into LDS sorted order (mid read #2, L2-hot)
    for (int i = t; i < segc; i += 512) {
        const int2 p = mid[start + i];
        const int pos = atomicAdd(&cptr[p.x & (BCOLS - 1)], 1);
        smid[pos] = p;
    }
    __syncthreads();

    // phase 4: quad-slice register aggregation.
    // quad lanes read the SAME smid[i] (LDS broadcast) and CONSECUTIVE 16B
    // chunks of the same pack row (quad-coalesced into one line request).
    {
        const int colq = t >> 2;
        const int slice = t & 3;
        float sacc[8];
#pragma unroll
        for (int m = 0; m < 8; m++) sacc[m] = 0.f;

        const int q0 = (colq == 0) ? 0 : cbase[colq - 1];
        const int q1 = cbase[colq];
        const unsigned short* pbase = pack16 + slice * 8;
#pragma unroll 4
        for (int i = q0; i < q1; i++) {
            const int2 p = smid[i];
            const unsigned row = ((unsigned)p.x) >> BSH;
            const float w = __int_as_float(p.y);
            const uint4 Q = *(const uint4*)(pbase + (size_t)row * 32);
            float2 f;
            f = h2f(Q.x); sacc[0] = fmaf(w, f.x, sacc[0]); sacc[1] = fmaf(w, f.y, sacc[1]);
            f = h2f(Q.y); sacc[2] = fmaf(w, f.x, sacc[2]); sacc[3] = fmaf(w, f.y, sacc[3]);
            f = h2f(Q.z); sacc[4] = fmaf(w, f.x, sacc[4]); sacc[5] = fmaf(w, f.y, sacc[5]);
            f = h2f(Q.w); sacc[6] = fmaf(w, f.x, sacc[6]); sacc[7] = fmaf(w, f.y, sacc[7]);
        }
        // publish disjoint slices (slice 3 is all row padding -> skip)
        if (slice < 3) {
#pragma unroll
            for (int m = 0; m < 8; m++) sfin[colq][slice * 8 + m] = sacc[m];
        }
    }
    __syncthreads();

    // epilogue per col: slice-0 lane of each quad owns the column.
    {
        const int colq = t >> 2;
        const int slice = t & 3;
        const int cc = b * BCOLS + colq;
        if (slice == 0 && cc < NN) {
            float s21[21];
#pragma unroll
            for (int m = 0; m < 21; m++) s21[m] = sfin[colq][m];
            // overflow fallback (never on this input)
            if (cntt > CAP) {
                const int n = min(*ovfn, OVCAP);
                for (int i = 0; i < n; i++) {
                    const int4 q = ovf[i];
                    if (q.x == cc) {
                        const unsigned row = (unsigned)q.y;
                        const float w = __int_as_float(q.z);
                        ACC_ROW16(pack16 + (size_t)row * 32);
                    }
                }
            }
            // self-loop (pack row already dinv-scaled) + exact fp32 dinv[c]
            {
                const float w = 1.0f;
                ACC_ROW16(pack16 + (size_t)cc * 32);
            }
            const float d = dinv[cc];
#pragma unroll
            for (int m = 0; m < 21; m++) sfin[colq][m] = s21[m] * d;
        }
    }
    __syncthreads();

    // fused MLP: col = t&127, hf = t>>7 (wave-uniform) -> scalar Mt loads.
    const int col = t & (BCOLS - 1);
    const int hf = t >> 7;              // 0..3, wave-uniform
    const int c = b * BCOLS + col;
    float s21[21];
#pragma unroll
    for (int m = 0; m < 21; m++) s21[m] = sfin[col][m];
    float o = 0.f;
    if (c < NN) {
        const int k0 = hf * 32;
#pragma unroll 2
        for (int k = k0; k < k0 + 32; k++) {
            const float* r = Mt + k * 24;
            float hsum = r[21];
#pragma unroll
            for (int m = 0; m < 21; m++) hsum = fmaf(s21[m], r[m], hsum);
            o = fmaf(fmaxf(hsum, 0.f), r[22], o);
        }
    }
    if (hf) po[hf - 1][col] = o;
    __syncthreads();
    if (hf == 0 && c < NN)
        out[c] = o + po[0][col] + po[1][col] + po[2][col] + b2[0];
}

// ===========================================================================
extern "C" void kernel_launch(void* const* d_in, const int* in_sizes, int n_in,
                              void* d_out, int out_size, void* d_ws, size_t ws_size,
                              hipStream_t stream) {
    const float* ux = (const float*)d_in[0];   // user_x  [N,3]
    const float* mx = (const float*)d_in[1];   // movie_x [N,18]
    const int* ei = (const int*)d_in[2];       // edge_index [2,E]
    const float* ew = (const float*)d_in[3];   // edge_attr [E]
    const float* Wu = (const float*)d_in[4];   // [3,64]
    const float* bu = (const float*)d_in[5];   // [64]
    const float* Wm = (const float*)d_in[6];   // [18,64]
    const float* bm = (const float*)d_in[7];   // [64]
    const float* W1 = (const float*)d_in[8];   // [128,128]
    const float* b1 = (const float*)d_in[9];   // [128]
    const float* W2 = (const float*)d_in[10];  // [128,1]
    const float* b2 = (const float*)d_in[11];  // [1]
    float* out = (float*)d_out;

    char* ws = (char*)d_ws;
    int*            gcur   = (int*)ws;                      // @0         3,128 B
    int*            ovfn   = (int*)(ws + 4096);             // @4096      4 B
    float*          Mt     = (float*)(ws + 8192);           // @8192      12,288 B
    float*          dinv   = (float*)(ws + 20480);          // @20480     400,000 B
    unsigned short* pack16 = (unsigned short*)(ws + 420480);// @420480    6,400,000 B (64B-aligned)
    int2*           mid    = (int2*)(ws + 6820480);         // @6820480   12,812,288 B (64B-aligned)
    int4*           ovf    = (int4*)(ws + 19632768);        // @19632768  262,144 B
    // total ~19.9 MB

    fuse_kernel<<<1, 128, 0, stream>>>(Wu, bu, Wm, bm, W1, b1, W2, Mt, gcur, ovfn);
    bscatter_kernel<<<SBLK, 256, 0, stream>>>(ei, ew, gcur, mid, ovf, ovfn);
    bdeg_pack_kernel<<<NBUCK, 256, 0, stream>>>(mid, gcur, ovfn, ovf, ux, mx, pack16, dinv);
    bagg_mlp_kernel<<<NBUCK, 512, 0, stream>>>(mid, gcur, ovfn, ovf, pack16, dinv, Mt, b2, out);
}